// Round 4
// baseline (442.892 us; speedup 1.0000x reference)
//
#include <hip/hip_runtime.h>

// MeshSDFLoss: P=16384 points vs F=16384 triangles, min sqdist + argmin + loss.
// Outputs (flat float32): [0]=loss, [1..P]=dist, [1+P..1+2P]=assoc (as float).
//
// R4: per-lane certified plane prune + per-lane LDS work queues.
//  - Executed pairs are BIT-EXACT vs the numpy fp32 reference (__f*_rn chain,
//    verified in R2: absmax 2.4e-7).
//  - CERTIFIED prune: per face store deflated unit normal n'(|n'|<=1 strictly)
//    and slack >= max_{q in tri} |n'.(q-a)| + pd rounding error. Then
//    dist(p,tri) >= |n'.(p-a)| - slack rigorously for ANY n' (sliver-safe:
//    bad normals get big slack automatically). Skip iff |pd| > thrP + slack
//    with thrP = sqrt(bestd)*1.0002+1e-5  ==>  dist^2 > bestd strictly
//    ==> skipped face can never be (or tie) the argmin. First-index
//    tie-break preserved: ascending face order per lane, strict <, packed
//    (distbits<<32|idx) u64 atomicMin across chunks/seed.
//  - Per-lane queues break the wave-unanimity wall: each lane enqueues only
//    ITS surviving faces (p1 ~ 0.4%) and drains them itself.

#define PTOT 16384
#define FTOT 16384
#define NCHUNK 16
#define FCHUNK (FTOT / NCHUNK)   // 1024 faces per chunk
#define TILE 256
#define BLOCK 256
#define QD 16                    // per-lane queue depth
#define ESTR 15                  // exec record floats: a(3) b(3) c(3) ab(3) ac(3)
#define SEEDN 128                // seed faces per point

// Bit-exact point-triangle squared distance (reference-identical rounding).
__device__ __forceinline__ float exec_pair(
    float px, float py, float pz,
    float ax, float ay, float az,
    float bx, float by, float bz,
    float cx, float cy, float cz,
    float abx, float aby, float abz,
    float acx, float acy, float acz)
{
#pragma clang fp contract(off)
    const float cbx = __fsub_rn(cx, bx), cby = __fsub_rn(cy, by), cbz = __fsub_rn(cz, bz);

    const float apx = __fsub_rn(px, ax), apy = __fsub_rn(py, ay), apz = __fsub_rn(pz, az);
    const float d1 = __fadd_rn(__fadd_rn(__fmul_rn(abx, apx), __fmul_rn(aby, apy)), __fmul_rn(abz, apz));
    const float d2 = __fadd_rn(__fadd_rn(__fmul_rn(acx, apx), __fmul_rn(acy, apy)), __fmul_rn(acz, apz));
    const float bpx = __fsub_rn(px, bx), bpy = __fsub_rn(py, by), bpz = __fsub_rn(pz, bz);
    const float d3 = __fadd_rn(__fadd_rn(__fmul_rn(abx, bpx), __fmul_rn(aby, bpy)), __fmul_rn(abz, bpz));
    const float d4 = __fadd_rn(__fadd_rn(__fmul_rn(acx, bpx), __fmul_rn(acy, bpy)), __fmul_rn(acz, bpz));
    const float cpx = __fsub_rn(px, cx), cpy = __fsub_rn(py, cy), cpz = __fsub_rn(pz, cz);
    const float d5 = __fadd_rn(__fadd_rn(__fmul_rn(abx, cpx), __fmul_rn(aby, cpy)), __fmul_rn(abz, cpz));
    const float d6 = __fadd_rn(__fadd_rn(__fmul_rn(acx, cpx), __fmul_rn(acy, cpy)), __fmul_rn(acz, cpz));

    const float vc_ = __fsub_rn(__fmul_rn(d1, d4), __fmul_rn(d3, d2));
    const float vb_ = __fsub_rn(__fmul_rn(d5, d2), __fmul_rn(d1, d6));
    const float va_ = __fsub_rn(__fmul_rn(d3, d6), __fmul_rn(d5, d4));

    const float den_ab = __fsub_rn(d1, d3);
    const float den_ac = __fsub_rn(d2, d6);
    const float t43    = __fsub_rn(d4, d3);
    const float t56    = __fsub_rn(d5, d6);
    const float den_bc = __fadd_rn(t43, t56);
    const float den_in = __fadd_rn(__fadd_rn(va_, vb_), vc_);

    const bool f_a  = (d1 <= 0.0f) && (d2 <= 0.0f);
    const bool f_b  = (d3 >= 0.0f) && (d4 <= d3);
    const bool f_c  = (d6 >= 0.0f) && (d5 <= d6);
    const bool f_ab = (vc_ <= 0.0f) && (d1 >= 0.0f) && (d3 <= 0.0f);
    const bool f_ac = (vb_ <= 0.0f) && (d2 >= 0.0f) && (d6 <= 0.0f);
    const bool f_bc = (va_ <= 0.0f) && (t43 >= 0.0f) && (t56 >= 0.0f);
    const bool vert = f_a || f_b || f_c;
    const bool e_ab = f_ab && !vert;
    const bool e_ac = f_ac && !vert && !f_ab;
    const bool e_bc = f_bc && !vert && !f_ab && !f_ac;
    const bool inte = !vert && !f_ab && !f_ac && !f_bc;

    const float num  = e_ab ? d1 : (e_ac ? d2 : (e_bc ? t43 : 1.0f));
    const float denr = e_ab ? den_ab : (e_ac ? den_ac : (e_bc ? den_bc : den_in));
    const float den  = (denr != 0.0f) ? denr : 1.0f;
    const float t    = __fdiv_rn(num, den);

    const float v_in = __fmul_rn(vb_, t);
    const float w_in = __fmul_rn(vc_, t);

    const float s1 = vert ? 0.0f : (inte ? v_in : t);
    const float s2 = inte ? w_in : 0.0f;
    const bool  sel_b = (!f_a && f_b) || e_bc;
    const bool  sel_c = !f_a && !f_b && f_c;
    const float e1x = e_ac ? acx : (e_bc ? cbx : abx);
    const float e1y = e_ac ? acy : (e_bc ? cby : aby);
    const float e1z = e_ac ? acz : (e_bc ? cbz : abz);
    const float bsx = sel_b ? bx : (sel_c ? cx : ax);
    const float bsy = sel_b ? by : (sel_c ? cy : ay);
    const float bsz = sel_b ? bz : (sel_c ? cz : az);
    const float qx = __fadd_rn(__fadd_rn(bsx, __fmul_rn(e1x, s1)), __fmul_rn(acx, s2));
    const float qy = __fadd_rn(__fadd_rn(bsy, __fmul_rn(e1y, s1)), __fmul_rn(acy, s2));
    const float qz = __fadd_rn(__fadd_rn(bsz, __fmul_rn(e1z, s1)), __fmul_rn(acz, s2));

    const float dxx = __fsub_rn(px, qx), dyy = __fsub_rn(py, qy), dzz = __fsub_rn(pz, qz);
    return __fadd_rn(__fadd_rn(__fmul_rn(dxx, dxx), __fmul_rn(dyy, dyy)), __fmul_rn(dzz, dzz));
}

// Seed: exact distance to SEEDN spread faces -> initializes best[] so the
// main kernel's thresholds start finite. Face loads are wave-uniform.
__global__ __launch_bounds__(BLOCK) void seed_kernel(
    const float* __restrict__ verts,
    const int* __restrict__ faces,
    const float* __restrict__ points,
    unsigned long long* __restrict__ best)
{
    const int p = blockIdx.x * BLOCK + threadIdx.x;
    const float px = points[p * 3 + 0];
    const float py = points[p * 3 + 1];
    const float pz = points[p * 3 + 2];

    float bestd = __builtin_inff();
    int   besti = 0;
    for (int k = 0; k < SEEDN; ++k) {
        const int f = k * (FTOT / SEEDN);   // ascending face index
        const int i0 = faces[f * 3 + 0];
        const int i1 = faces[f * 3 + 1];
        const int i2 = faces[f * 3 + 2];
        const float ax = verts[i0 * 3 + 0], ay = verts[i0 * 3 + 1], az = verts[i0 * 3 + 2];
        const float bx = verts[i1 * 3 + 0], by = verts[i1 * 3 + 1], bz = verts[i1 * 3 + 2];
        const float cx = verts[i2 * 3 + 0], cy = verts[i2 * 3 + 1], cz = verts[i2 * 3 + 2];
        const float abx = __fsub_rn(bx, ax), aby = __fsub_rn(by, ay), abz = __fsub_rn(bz, az);
        const float acx = __fsub_rn(cx, ax), acy = __fsub_rn(cy, ay), acz = __fsub_rn(cz, az);
        const float d = exec_pair(px, py, pz, ax, ay, az, bx, by, bz, cx, cy, cz,
                                  abx, aby, abz, acx, acy, acz);
        if (d < bestd) { bestd = d; besti = f; }
    }
    const unsigned long long packed =
        ((unsigned long long)__float_as_uint(bestd) << 32) | (unsigned int)besti;
    atomicMin(&best[p], packed);
}

__global__ __launch_bounds__(BLOCK) void sdf_main_kernel(
    const float* __restrict__ verts,
    const int* __restrict__ faces,
    const float* __restrict__ points,
    unsigned long long* __restrict__ best)
{
#pragma clang fp contract(off)
    __shared__ float4  sScan[TILE];          // {nhx, nhy, nhz, -nh.a}
    __shared__ float   sSlack[TILE];
    __shared__ float   sExec[TILE * ESTR];   // stride 15 (odd -> bank-dispersed)
    __shared__ unsigned sQ[BLOCK * QD];

    const int tid = threadIdx.x;
    const int p = blockIdx.x * BLOCK + tid;
    const float px = points[p * 3 + 0];
    const float py = points[p * 3 + 1];
    const float pz = points[p * 3 + 2];

    float bestd = __builtin_inff();
    int   besti = 0;
    float pruneS = __builtin_inff();
    float thrP   = __builtin_inff();

    const int fbase = blockIdx.y * FCHUNK;
    int cnt = 0;

    for (int t0 = 0; t0 < FCHUNK; t0 += TILE) {
        __syncthreads();
        {   // ---- stage faces [fbase+t0, +TILE) ----
            const int f  = fbase + t0 + tid;
            const int i0 = faces[f * 3 + 0];
            const int i1 = faces[f * 3 + 1];
            const int i2 = faces[f * 3 + 2];
            const float ax = verts[i0 * 3 + 0], ay = verts[i0 * 3 + 1], az = verts[i0 * 3 + 2];
            const float bx = verts[i1 * 3 + 0], by = verts[i1 * 3 + 1], bz = verts[i1 * 3 + 2];
            const float cx = verts[i2 * 3 + 0], cy = verts[i2 * 3 + 1], cz = verts[i2 * 3 + 2];
            const float abx = __fsub_rn(bx, ax), aby = __fsub_rn(by, ay), abz = __fsub_rn(bz, az);
            const float acx = __fsub_rn(cx, ax), acy = __fsub_rn(cy, ay), acz = __fsub_rn(cz, az);
            float* e = &sExec[tid * ESTR];
            e[0]  = ax;  e[1]  = ay;  e[2]  = az;
            e[3]  = bx;  e[4]  = by;  e[5]  = bz;
            e[6]  = cx;  e[7]  = cy;  e[8]  = cz;
            e[9]  = abx; e[10] = aby; e[11] = abz;
            e[12] = acx; e[13] = acy; e[14] = acz;
            // Certified prune record (approx math OK; slack certifies it):
            const float nx = aby * acz - abz * acy;
            const float ny = abz * acx - abx * acz;
            const float nz = abx * acy - aby * acx;
            const float nn = nx * nx + ny * ny + nz * nz;
            const float rin = rsqrtf(nn) * 0.99999f;     // deflate: |nh| <= 1 certified
            const float hx = nx * rin, hy = ny * rin, hz = nz * rin;
            const float md0 = -(hx * ax + hy * ay + hz * az);
            sScan[tid] = make_float4(hx, hy, hz, md0);
            const float sab = fabsf(hx * abx + hy * aby + hz * abz);
            const float sac = fabsf(hx * acx + hy * acy + hz * acz);
            sSlack[tid] = fmaxf(sab, sac) * 1.0001f + 2e-6f;  // covers dot + pd rounding
        }
        __syncthreads();

        // refresh threshold from cross-chunk achieved distance (exact values)
        {
            const unsigned long long gb =
                __hip_atomic_load(&best[p], __ATOMIC_RELAXED, __HIP_MEMORY_SCOPE_AGENT);
            const float gs = sqrtf(__uint_as_float((unsigned)(gb >> 32))); // NaN if sentinel
            pruneS = fminf(pruneS, gs);                                    // minNum ignores NaN
            thrP   = __fmaf_rn(pruneS, 1.0002f, 1e-5f);
        }

        auto drain = [&]() {
            for (int k = 0; k < QD; ++k) {
                if (!__ballot(k < cnt)) break;
                if (k < cnt) {
                    const int jq = (int)sQ[tid * QD + k];
                    const float* e = &sExec[jq * ESTR];
                    const float dist = exec_pair(px, py, pz,
                        e[0], e[1], e[2], e[3], e[4], e[5], e[6], e[7], e[8],
                        e[9], e[10], e[11], e[12], e[13], e[14]);
                    if (dist < bestd) {
                        bestd = dist; besti = fbase + t0 + jq;
                        pruneS = fminf(pruneS, sqrtf(dist));
                        thrP   = __fmaf_rn(pruneS, 1.0002f, 1e-5f);
                    }
                }
            }
            cnt = 0;
        };

#pragma unroll 4
        for (int j = 0; j < TILE; ++j) {
            const float4 sc = sScan[j];
            const float  sl = sSlack[j];
            const float pd = __fmaf_rn(sc.x, px, __fmaf_rn(sc.y, py, __fmaf_rn(sc.z, pz, sc.w)));
            // NaN pd (degenerate face) -> compare false -> survive (conservative)
            const bool sv = !(fabsf(pd) > __fadd_rn(thrP, sl));
            if (sv) { sQ[tid * QD + cnt] = (unsigned)j; ++cnt; }
            if (__ballot(cnt >= QD)) drain();
        }
        drain();
    }

    const unsigned long long packed =
        ((unsigned long long)__float_as_uint(bestd) << 32) | (unsigned int)besti;
    atomicMin(&best[p], packed);
}

__global__ __launch_bounds__(BLOCK) void sdf_final_kernel(
    const unsigned long long* __restrict__ best, float* __restrict__ out)
{
    __shared__ float wsum[BLOCK / 64];
    const int p = blockIdx.x * BLOCK + threadIdx.x;
    const unsigned long long v = best[p];
    const float d = __uint_as_float((unsigned)(v >> 32));
    const int idx = (int)(unsigned)(v & 0xffffffffull);
    out[1 + p] = d;
    out[1 + PTOT + p] = (float)idx;

    float s = d;
    for (int off = 32; off > 0; off >>= 1) s += __shfl_down(s, off, 64);
    const int lane = threadIdx.x & 63;
    const int w = threadIdx.x >> 6;
    if (lane == 0) wsum[w] = s;
    __syncthreads();
    if (threadIdx.x == 0) {
        float tsum = 0.0f;
        for (int i = 0; i < BLOCK / 64; ++i) tsum += wsum[i];
        atomicAdd(&out[0], tsum);
    }
}

extern "C" void kernel_launch(void* const* d_in, const int* in_sizes, int n_in,
                              void* d_out, int out_size, void* d_ws, size_t ws_size,
                              hipStream_t stream) {
    const float* verts  = (const float*)d_in[0];
    const int*   faces  = (const int*)d_in[1];
    const float* points = (const float*)d_in[2];
    float* out = (float*)d_out;
    unsigned long long* best = (unsigned long long*)d_ws;

    // 0xFF.. = max u64 sentinel (> any packed finite result)
    hipMemsetAsync(best, 0xFF, (size_t)PTOT * sizeof(unsigned long long), stream);
    hipMemsetAsync(out, 0, sizeof(float), stream);  // loss accumulator

    seed_kernel<<<PTOT / BLOCK, BLOCK, 0, stream>>>(verts, faces, points, best);
    dim3 grid(PTOT / BLOCK, NCHUNK);
    sdf_main_kernel<<<grid, BLOCK, 0, stream>>>(verts, faces, points, best);
    sdf_final_kernel<<<PTOT / BLOCK, BLOCK, 0, stream>>>(best, out);
}